// Round 6
// baseline (139.909 us; speedup 1.0000x reference)
//
#include <hip/hip_runtime.h>
#include <hip/hip_cooperative_groups.h>
#include <math.h>

namespace cg = cooperative_groups;

// PostProcess: B=16, Q=2048, C=2. ONE cooperative kernel, grid = B*8 blocks x 1024.
//  Phase 1 (slice==0 blocks): softmax keys -> ballot compact -> register bitonic sort -> ws
//  Phase 2 (all blocks):      pairwise-IoU suppression bit matrix (ragged) -> ws
//  Phase 3 (slice==0 blocks): single-wave greedy bitmask scan + scatter + epilogue
// image = blockIdx%B, slice = blockIdx/B  => image b's 8 blocks all on XCD b%8 (L2 locality).
// ws: M u32[16]@0 | sidx u16[16][1024]@256 | SoA f32[16][5][1024]@33024
//     | mat u32[16][17408]@360704 | keep u8[16][2048]@1474816   (~1.44 MB)

#define QN   2048
#define NS   1024     // fast-path max valid boxes (E[M]=549, sd~20; M>1024 ~23 sigma)
#define MATW 17408    // ragged u32 words/image = 64 * sum_{wb<16}(32-2wb)

__device__ __forceinline__ int rb32(int wb) { return 64 * wb * (33 - wb); }

__device__ __forceinline__ unsigned long long shfl_xor_u64(unsigned long long x, int m) {
    int lo = __shfl_xor((int)(unsigned)(x & 0xffffffffull), m, 64);
    int hi = __shfl_xor((int)(unsigned)(x >> 32), m, 64);
    return ((unsigned long long)(unsigned)hi << 32) | (unsigned)lo;
}

// ascending sort == score desc, idx asc (stable); invalid -> tail. Validity returned
// explicitly (valid key's top bit is SET -- R3 bug).
__device__ __forceinline__ unsigned long long score_key(float2 l, int q, bool* valid_out) {
    float mx = fmaxf(l.x, l.y), mn = fminf(l.x, l.y);
    float e = expf(mn - mx);
    float score = 1.0f / (1.0f + e);                 // max softmax prob (exact ref order)
    bool valid = (l.x >= l.y) && (score >= 0.7f);    // argmax tie -> class 0
    *valid_out = valid;
    unsigned sbits = valid ? __float_as_uint(score) : 0u;
    return ((unsigned long long)(~sbits) << 32) | (unsigned)q;
}

__global__ __launch_bounds__(1024) void postproc_coop(
    const float* __restrict__ logits, const float* __restrict__ pboxes,
    const int* __restrict__ img_h_p, const int* __restrict__ img_w_p,
    unsigned* __restrict__ wsM, unsigned short* __restrict__ wsidx,
    float* __restrict__ wsoa, unsigned* __restrict__ wmat,
    unsigned char* __restrict__ wkeep, float* __restrict__ out, int B)
{
    cg::grid_group grid = cg::this_grid();
    __shared__ __align__(16) char smem[20608];   // phase-overlaid union

    const int blk = blockIdx.x;
    const int b = blk % B;            // image
    const int slice = blk / B;        // 0..7
    const int tid = threadIdx.x, lane = tid & 63, wave = tid >> 6;
    const float sw = (float)(*img_w_p), sh = (float)(*img_h_p);

    // ================= Phase 1: compact + sort + SoA (slice 0 only) =================
    if (slice == 0) {
        unsigned long long* skey = (unsigned long long*)smem;           // u64[2048]
        unsigned char* ssupp = (unsigned char*)(smem + 16384);          // fallback only
        int* sMp = (int*)(smem + 18432);
        if (tid == 0) *sMp = 0;
        __syncthreads();

        const unsigned long long lmask_lt = (1ull << lane) - 1ull;
#pragma unroll
        for (int qq = 0; qq < 2; ++qq) {
            int q = tid + qq * 1024;
            float2 l = ((const float2*)logits)[b * QN + q];
            bool valid;
            unsigned long long key = score_key(l, q, &valid);
            unsigned long long mb = __ballot(valid);
            int base = 0;
            if (lane == 0 && mb) base = atomicAdd(sMp, __popcll(mb));
            base = __shfl(base, 0, 64);
            if (valid) {
                int slot = base + __popcll(mb & lmask_lt);
                if (slot < NS) skey[slot] = key;
            }
        }
        __syncthreads();
        const int M = *sMp;

        if (M <= NS) {
            // register bitonic sort of NS u64, 1 elem/thread (verified R4/R5)
            unsigned long long v = (tid < M) ? skey[tid] : ~0ull;
            __syncthreads();
#pragma unroll
            for (int k = 2; k <= 64; k <<= 1) {
                bool dir = ((tid & k) == 0);
#pragma unroll
                for (int j = k >> 1; j > 0; j >>= 1) {
                    unsigned long long o = shfl_xor_u64(v, j);
                    bool takeMin = (dir == ((tid & j) == 0));
                    v = ((v < o) == takeMin) ? v : o;
                }
            }
            for (int k = 128; k <= NS; k <<= 1) {
                bool dir = ((tid & k) == 0);
                for (int j = k >> 1; j >= 64; j >>= 1) {
                    skey[tid] = v;
                    __syncthreads();
                    unsigned long long o = skey[tid ^ j];
                    bool takeMin = (dir == ((tid & j) == 0));
                    v = ((v < o) == takeMin) ? v : o;
                    __syncthreads();
                }
#pragma unroll
                for (int j = 32; j > 0; j >>= 1) {
                    unsigned long long o = shfl_xor_u64(v, j);
                    bool takeMin = (dir == ((tid & j) == 0));
                    v = ((v < o) == takeMin) ? v : o;
                }
            }
            int qi = (int)((unsigned)v & 0xffffu);
            wsidx[b * NS + tid] = (unsigned short)qi;
            float x1 = 0.f, y1 = 0.f, x2 = 0.f, y2 = 0.f, ar = 0.f;
            if (tid < M) {
                float4 pb = ((const float4*)pboxes)[b * QN + qi];
                x1 = (pb.x - 0.5f * pb.z) * sw;
                y1 = (pb.y - 0.5f * pb.w) * sh;
                x2 = (pb.x + 0.5f * pb.z) * sw;
                y2 = (pb.y + 0.5f * pb.w) * sh;
                ar = fmaxf(x2 - x1, 0.f) * fmaxf(y2 - y1, 0.f);
            }
            float* soa = wsoa + (long)b * 5 * NS;
            soa[tid] = x1; soa[NS + tid] = y1; soa[2 * NS + tid] = x2;
            soa[3 * NS + tid] = y2; soa[4 * NS + tid] = ar;
            if (tid == 0) wsM[b] = (unsigned)M;
        } else {
            // -------- Fallback (M > NS, ~never): LDS sort + barrier greedy -> wkeep ----
            for (int q = tid; q < QN; q += 1024) {
                float2 l = ((const float2*)logits)[b * QN + q];
                bool valid;
                skey[q] = score_key(l, q, &valid);
                wkeep[b * QN + q] = 0;
            }
            __syncthreads();
            for (int k = 2; k <= QN; k <<= 1)
                for (int j = k >> 1; j > 0; j >>= 1) {
                    int i = ((tid & ~(j - 1)) << 1) | (tid & (j - 1));
                    int p = i | j;
                    bool up = ((i & k) == 0);
                    unsigned long long a = skey[i], c2 = skey[p];
                    if ((a > c2) == up) { skey[i] = c2; skey[p] = a; }
                    __syncthreads();
                }
            for (int s = tid; s < M; s += 1024) ssupp[s] = 0;
            __syncthreads();
            for (int i = 0; i < M; ++i) {
                __syncthreads();
                if (ssupp[i]) continue;
                int ia = (unsigned short)(unsigned)skey[i];
                float4 pa = ((const float4*)pboxes)[b * QN + ia];
                float ax1 = (pa.x - 0.5f * pa.z) * sw, ay1 = (pa.y - 0.5f * pa.w) * sh;
                float ax2 = (pa.x + 0.5f * pa.z) * sw, ay2 = (pa.y + 0.5f * pa.w) * sh;
                float areaA = fmaxf(ax2 - ax1, 0.f) * fmaxf(ay2 - ay1, 0.f);
                for (int jj = i + 1 + tid; jj < M; jj += 1024) {
                    int jb = (unsigned short)(unsigned)skey[jj];
                    float4 pq = ((const float4*)pboxes)[b * QN + jb];
                    float bx1 = (pq.x - 0.5f * pq.z) * sw, by1 = (pq.y - 0.5f * pq.w) * sh;
                    float bx2 = (pq.x + 0.5f * pq.z) * sw, by2 = (pq.y + 0.5f * pq.w) * sh;
                    float ltx = fmaxf(ax1, bx1), lty = fmaxf(ay1, by1);
                    float rbx = fminf(ax2, bx2), rby = fminf(ay2, by2);
                    float wx = fmaxf(rbx - ltx, 0.f), wy = fmaxf(rby - lty, 0.f);
                    float inter = wx * wy;
                    float areaB = fmaxf(bx2 - bx1, 0.f) * fmaxf(by2 - by1, 0.f);
                    float uni = areaA + areaB - inter;
                    if (inter / fmaxf(uni, 1e-9f) > 0.5f) ssupp[jj] = 1;
                }
            }
            __syncthreads();
            for (int s = tid; s < M; s += 1024)
                if (!ssupp[s]) wkeep[b * QN + (unsigned short)(unsigned)skey[s]] = 1;
            if (tid == 0) wsM[b] = (unsigned)M;
        }
    }

    grid.sync();

    // ================= Phase 2: suppression bit matrix (all blocks) =================
    {
        const int M = (int)wsM[b];
        if (M <= NS) {
            float* sx1 = (float*)smem;
            float* sy1 = (float*)(smem + 4096);
            float* sx2 = (float*)(smem + 8192);
            float* sy2 = (float*)(smem + 12288);
            float* sar = (float*)(smem + 16384);
            const float* soa = wsoa + (long)b * 5 * NS;
            sx1[tid] = soa[tid];          sy1[tid] = soa[NS + tid];
            sx2[tid] = soa[2 * NS + tid]; sy2[tid] = soa[3 * NS + tid];
            sar[tid] = soa[4 * NS + tid];
            __syncthreads();

            unsigned* mat = wmat + (long)b * MATW;
            const int NG = (M + 3) >> 2;
            const int W64 = (M + 63) >> 6;
            for (int gi = slice * 16 + wave; gi < NG; gi += 128) {
                const int g = gi << 2;
                const int nr = min(4, M - g);
                const int wb = g >> 6;
                const int rl = 32 - 2 * wb;
                float ax1[4], ay1[4], ax2[4], ay2[4], aar[4];
                int rbase[4];
#pragma unroll
                for (int r = 0; r < 4; ++r) {
                    int i = g + min(r, nr - 1);
                    ax1[r] = sx1[i]; ay1[r] = sy1[i];
                    ax2[r] = sx2[i]; ay2[r] = sy2[i]; aar[r] = sar[i];
                    rbase[r] = rb32(wb) + ((g + r) & 63) * rl;
                }
                for (int w = wb; w < W64; ++w) {
                    int j = (w << 6) | lane;
                    float bx1 = sx1[j], by1 = sy1[j], bx2 = sx2[j], by2 = sy2[j], bar = sar[j];
#pragma unroll
                    for (int r = 0; r < 4; ++r) {
                        float ltx = fmaxf(ax1[r], bx1), lty = fmaxf(ay1[r], by1);
                        float rbx = fminf(ax2[r], bx2), rby = fminf(ay2[r], by2);
                        float wx = fmaxf(rbx - ltx, 0.f), wy = fmaxf(rby - lty, 0.f);
                        float inter = wx * wy;
                        float uni = aar[r] + bar - inter;       // exact ref op order
                        float iou = inter / fmaxf(uni, 1e-9f);  // exact IEEE div
                        bool sup = (iou > 0.5f) && (j > g + r);
                        unsigned long long bal = __ballot(sup);
                        if (lane == 0 && r < nr)
                            *(unsigned long long*)(mat + rbase[r] + 2 * (w - wb)) = bal;
                    }
                }
            }
        }
    }

    grid.sync();

    // ================= Phase 3: greedy scan + scatter + epilogue (slice 0) ==========
    if (slice == 0) {
        unsigned char* keepq = (unsigned char*)smem;       // [2048]
        unsigned* skm = (unsigned*)(smem + 2048);          // [32]
        const int M = (int)wsM[b];

        if (M <= NS) {
            keepq[tid] = 0; keepq[tid + 1024] = 0;
            if (tid < 64) {
                if (tid < 32) skm[tid] = 0;
                const unsigned* gm = wmat + (long)b * MATW;
                unsigned rem = 0;
                const int Ms = __builtin_amdgcn_readfirstlane(M);
                const int C = (Ms + 31) >> 5;
                unsigned rcur[32], rnxt[32];
                if (C > 0) {
                    int Lc = min(tid, 31);
#pragma unroll
                    for (int t = 0; t < 32; ++t) rcur[t] = gm[Lc + t * 32];
                }
                for (int c = 0; c < C; ++c) {
                    if (c + 1 < C) {                      // prefetch next chunk
                        int cn = c + 1, wbn = cn >> 1, rln = 32 - 2 * wbn;
                        int Lcn = min(max(tid, 2 * wbn), 31);
                        int rb0n = rb32(wbn) + ((cn & 1) << 5) * rln + (Lcn - 2 * wbn);
#pragma unroll
                        for (int t = 0; t < 32; ++t) rnxt[t] = gm[rb0n + t * rln];
                    }
                    unsigned rw = (unsigned)__builtin_amdgcn_readlane((int)rem, c);
                    unsigned keepmask = 0;
                    int lim = min(32, Ms - (c << 5));
#pragma unroll
                    for (int t = 0; t < 32; ++t) {
                        if (t < lim && !((rw >> t) & 1u)) {   // wave-uniform predicate
                            keepmask |= (1u << t);
                            rem |= rcur[t];
                            rw |= (unsigned)__builtin_amdgcn_readlane((int)rcur[t], c);
                        }
                    }
                    if (tid == 0) skm[c] = keepmask;
                    if (c + 1 < C) {
#pragma unroll
                        for (int t = 0; t < 32; ++t) rcur[t] = rnxt[t];
                    }
                }
            }
            __syncthreads();
            for (int s = tid; s < M; s += 1024)
                if ((skm[s >> 5] >> (s & 31)) & 1u) keepq[wsidx[b * NS + s]] = 1;
            __syncthreads();
        } else {
            keepq[tid] = wkeep[b * QN + tid];
            keepq[tid + 1024] = wkeep[b * QN + tid + 1024];
            __syncthreads();
        }

        // epilogue: all outputs (d_out poisoned every call)
        const long BQ = (long)B * QN;
#pragma unroll
        for (int qq = 0; qq < 2; ++qq) {
            int q = tid + qq * 1024;
            int base = b * QN + q;
            float2 l = ((const float2*)logits)[base];
            float e = expf(fminf(l.x, l.y) - fmaxf(l.x, l.y));
            float score = 1.0f / (1.0f + e);
            float4 pb = ((const float4*)pboxes)[base];
            float x1 = (pb.x - 0.5f * pb.z) * sw, y1 = (pb.y - 0.5f * pb.w) * sh;
            float x2 = (pb.x + 0.5f * pb.z) * sw, y2 = (pb.y + 0.5f * pb.w) * sh;
            int kp = keepq[q];
            out[base] = kp ? score : 0.f;
            out[BQ * 5 + base] = kp ? 1.f : 0.f;
            float4 ob;
            ob.x = kp ? truncf(x1) : 0.f;
            ob.y = kp ? truncf(y1) : 0.f;
            ob.z = kp ? truncf(x2) : 0.f;
            ob.w = kp ? truncf(y2) : 0.f;
            ((float4*)(out + BQ))[base] = ob;
        }
    }
}

extern "C" void kernel_launch(void* const* d_in, const int* in_sizes, int n_in,
                              void* d_out, int out_size, void* d_ws, size_t ws_size,
                              hipStream_t stream) {
    const float* logits = (const float*)d_in[0];
    const float* pboxes = (const float*)d_in[1];
    const int*   img_h  = (const int*)d_in[2];
    const int*   img_w  = (const int*)d_in[3];
    float* out = (float*)d_out;
    int B = in_sizes[0] / (QN * 2);   // 16

    char* ws = (char*)d_ws;                          // needs ~1.44 MB
    unsigned*       wsM   = (unsigned*)(ws + 0);
    unsigned short* wsidx = (unsigned short*)(ws + 256);
    float*          wsoa  = (float*)(ws + 33024);
    unsigned*       wmat  = (unsigned*)(ws + 360704);
    unsigned char*  wkeep = (unsigned char*)(ws + 1474816);

    void* args[] = { (void*)&logits, (void*)&pboxes, (void*)&img_h, (void*)&img_w,
                     (void*)&wsM, (void*)&wsidx, (void*)&wsoa, (void*)&wmat,
                     (void*)&wkeep, (void*)&out, (void*)&B };
    hipLaunchCooperativeKernel((void*)postproc_coop, dim3(B * 8), dim3(1024),
                               args, 0, stream);
}

// Round 7
// 108.853 us; speedup vs baseline: 1.2853x; 1.2853x over previous
//
#include <hip/hip_runtime.h>
#include <math.h>

// PostProcess: B=16, Q=2048, C=2. Two-kernel pipeline:
//  kbuild (B*8 blocks): per block -> redundant compact + O(M^2) rank (replaces sort!)
//                       -> sorted SoA in LDS -> 1/8 slice of IoU suppression bit matrix
//  kscan  (B blocks):   single-wave greedy bitmask scan + keep scatter + epilogue
// blk->(b=blk%B, slice=blk/B): image b's 8 slices land on XCD b%8 (L2 locality).
// ws: M u32[16]@0 | sidx u16[16][1024]@256 | mat u32[16][17408]@33024 | keep u8@1147136

#define QN   2048
#define NS   1024     // fast-path max valid boxes (E[M]=549, sd~20; M>NS ~23 sigma)
#define MATW 17408    // ragged u32 words/image = 64 * sum_{wb<16}(32-2wb)

__device__ __forceinline__ int rb32(int wb) { return 64 * wb * (33 - wb); }

// ascending key order == score desc, idx asc (stable); invalid -> tail. Validity
// returned explicitly (valid key's top bit is SET -- R3 bug).
__device__ __forceinline__ unsigned long long score_key(float2 l, int q, bool* valid_out) {
    float mx = fmaxf(l.x, l.y), mn = fminf(l.x, l.y);
    float e = expf(mn - mx);
    float score = 1.0f / (1.0f + e);                 // max softmax prob (exact ref order)
    bool valid = (l.x >= l.y) && (score >= 0.7f);    // argmax tie -> class 0
    *valid_out = valid;
    unsigned sbits = valid ? __float_as_uint(score) : 0u;
    return ((unsigned long long)(~sbits) << 32) | (unsigned)q;
}

// ---------------- Kernel 1: compact + rank + matrix slice ----------------
__global__ __launch_bounds__(1024) void kbuild(
    const float* __restrict__ logits, const float* __restrict__ pboxes,
    const int* __restrict__ img_h_p, const int* __restrict__ img_w_p,
    unsigned* __restrict__ wsM, unsigned short* __restrict__ wsidx,
    unsigned* __restrict__ wmat, unsigned char* __restrict__ wkeep, int B)
{
    // fast path:  skey u64[NS]@0 | sx1@8192 sy1@12288 sx2@16384 sy2@20480 sar@24576
    //             | sidxl u16[NS]@28672 | sM@30720
    // fallback:   skeyF u64[QN]@0 (16KB) | ssupp u8[QN]@16384 | sM@30720
    __shared__ __align__(16) char smem[30724];
    unsigned long long* skey = (unsigned long long*)smem;
    float* sx1 = (float*)(smem + 8192);
    float* sy1 = (float*)(smem + 12288);
    float* sx2 = (float*)(smem + 16384);
    float* sy2 = (float*)(smem + 20480);
    float* sar = (float*)(smem + 24576);
    unsigned short* sidxl = (unsigned short*)(smem + 28672);
    int* sMp = (int*)(smem + 30720);

    const int blk = blockIdx.x;
    const int b = blk % B, slice = blk / B;
    const int tid = threadIdx.x, lane = tid & 63, wave = tid >> 6;
    const float sw = (float)(*img_w_p), sh = (float)(*img_h_p);

    if (tid == 0) *sMp = 0;
    __syncthreads();

    // compact valid keys (order block-dependent; ranks make the result deterministic)
    const unsigned long long lmask_lt = (1ull << lane) - 1ull;
#pragma unroll
    for (int qq = 0; qq < 2; ++qq) {
        int q = tid + qq * 1024;
        float2 l = ((const float2*)logits)[b * QN + q];
        bool valid;
        unsigned long long key = score_key(l, q, &valid);
        unsigned long long mb = __ballot(valid);
        int base = 0;
        if (lane == 0 && mb) base = atomicAdd(sMp, __popcll(mb));
        base = __shfl(base, 0, 64);
        if (valid) {
            int slot = base + __popcll(mb & lmask_lt);
            if (slot < NS) skey[slot] = key;
        }
    }
    __syncthreads();
    const int M = *sMp;

    if (M <= NS) {
        // zero sorted arrays (padding slots must give iou=0)
        sx1[tid] = 0.f; sy1[tid] = 0.f; sx2[tid] = 0.f; sy2[tid] = 0.f; sar[tid] = 0.f;
        sidxl[tid] = 0;
        __syncthreads();

        // rank = #{j: key_j < key_i}  (exact stable-sort permutation; keys unique)
        if (tid < M) {
            unsigned long long my = skey[tid];
            int r = 0, j = 0;
            for (; j + 4 <= M; j += 4)
                r += (int)(skey[j] < my) + (int)(skey[j + 1] < my)
                   + (int)(skey[j + 2] < my) + (int)(skey[j + 3] < my);
            for (; j < M; ++j) r += (int)(skey[j] < my);
            int qi = (int)((unsigned)my & 0xffffu);
            float4 pb = ((const float4*)pboxes)[b * QN + qi];
            float x1 = (pb.x - 0.5f * pb.z) * sw;
            float y1 = (pb.y - 0.5f * pb.w) * sh;
            float x2 = (pb.x + 0.5f * pb.z) * sw;
            float y2 = (pb.y + 0.5f * pb.w) * sh;
            sx1[r] = x1; sy1[r] = y1; sx2[r] = x2; sy2[r] = y2;
            sar[r] = fmaxf(x2 - x1, 0.f) * fmaxf(y2 - y1, 0.f);
            sidxl[r] = (unsigned short)qi;
        }
        __syncthreads();

        if (slice == 0) {
            wsidx[b * NS + tid] = sidxl[tid];
            if (tid == 0) wsM[b] = (unsigned)M;
        }

        // matrix slice (body verified R5/R6)
        unsigned* mat = wmat + (long)b * MATW;
        const int NG = (M + 3) >> 2;
        const int W64 = (M + 63) >> 6;
        for (int gi = slice * 16 + wave; gi < NG; gi += 128) {
            const int g = gi << 2;
            const int nr = min(4, M - g);
            const int wb = g >> 6;
            const int rl = 32 - 2 * wb;
            float ax1[4], ay1[4], ax2[4], ay2[4], aar[4];
            int rbase[4];
#pragma unroll
            for (int r = 0; r < 4; ++r) {
                int i = g + min(r, nr - 1);
                ax1[r] = sx1[i]; ay1[r] = sy1[i];
                ax2[r] = sx2[i]; ay2[r] = sy2[i]; aar[r] = sar[i];
                rbase[r] = rb32(wb) + ((g + r) & 63) * rl;
            }
            for (int w = wb; w < W64; ++w) {
                int j = (w << 6) | lane;
                float bx1 = sx1[j], by1 = sy1[j], bx2 = sx2[j], by2 = sy2[j], bar = sar[j];
#pragma unroll
                for (int r = 0; r < 4; ++r) {
                    float ltx = fmaxf(ax1[r], bx1), lty = fmaxf(ay1[r], by1);
                    float rbx = fminf(ax2[r], bx2), rby = fminf(ay2[r], by2);
                    float wx = fmaxf(rbx - ltx, 0.f), wy = fmaxf(rby - lty, 0.f);
                    float inter = wx * wy;
                    float uni = aar[r] + bar - inter;       // exact ref op order
                    float iou = inter / fmaxf(uni, 1e-9f);  // exact IEEE div
                    bool sup = (iou > 0.5f) && (j > g + r);
                    unsigned long long bal = __ballot(sup);
                    if (lane == 0 && r < nr)
                        *(unsigned long long*)(mat + rbase[r] + 2 * (w - wb)) = bal;
                }
            }
        }
    } else if (slice == 0) {
        // ---- Fallback (M > NS, ~never): full LDS sort + barrier greedy -> wkeep ----
        unsigned long long* skeyF = (unsigned long long*)smem;
        unsigned char* ssupp = (unsigned char*)(smem + 16384);
        for (int q = tid; q < QN; q += 1024) {
            float2 l = ((const float2*)logits)[b * QN + q];
            bool valid;
            skeyF[q] = score_key(l, q, &valid);
            wkeep[b * QN + q] = 0;
        }
        __syncthreads();
        for (int k = 2; k <= QN; k <<= 1)
            for (int j = k >> 1; j > 0; j >>= 1) {
                int i = ((tid & ~(j - 1)) << 1) | (tid & (j - 1));
                int p = i | j;
                bool up = ((i & k) == 0);
                unsigned long long a = skeyF[i], c2 = skeyF[p];
                if ((a > c2) == up) { skeyF[i] = c2; skeyF[p] = a; }
                __syncthreads();
            }
        for (int s = tid; s < M; s += 1024) ssupp[s] = 0;
        __syncthreads();
        for (int i = 0; i < M; ++i) {
            __syncthreads();
            if (ssupp[i]) continue;
            int ia = (unsigned short)(unsigned)skeyF[i];
            float4 pa = ((const float4*)pboxes)[b * QN + ia];
            float ax1 = (pa.x - 0.5f * pa.z) * sw, ay1 = (pa.y - 0.5f * pa.w) * sh;
            float ax2 = (pa.x + 0.5f * pa.z) * sw, ay2 = (pa.y + 0.5f * pa.w) * sh;
            float areaA = fmaxf(ax2 - ax1, 0.f) * fmaxf(ay2 - ay1, 0.f);
            for (int jj = i + 1 + tid; jj < M; jj += 1024) {
                int jb = (unsigned short)(unsigned)skeyF[jj];
                float4 pq = ((const float4*)pboxes)[b * QN + jb];
                float bx1 = (pq.x - 0.5f * pq.z) * sw, by1 = (pq.y - 0.5f * pq.w) * sh;
                float bx2 = (pq.x + 0.5f * pq.z) * sw, by2 = (pq.y + 0.5f * pq.w) * sh;
                float ltx = fmaxf(ax1, bx1), lty = fmaxf(ay1, by1);
                float rbx = fminf(ax2, bx2), rby = fminf(ay2, by2);
                float wx = fmaxf(rbx - ltx, 0.f), wy = fmaxf(rby - lty, 0.f);
                float inter = wx * wy;
                float areaB = fmaxf(bx2 - bx1, 0.f) * fmaxf(by2 - by1, 0.f);
                float uni = areaA + areaB - inter;
                if (inter / fmaxf(uni, 1e-9f) > 0.5f) ssupp[jj] = 1;
            }
        }
        __syncthreads();
        for (int s = tid; s < M; s += 1024)
            if (!ssupp[s]) wkeep[b * QN + (unsigned short)(unsigned)skeyF[s]] = 1;
        if (tid == 0) wsM[b] = (unsigned)M;
    }
}

// ---------------- Kernel 2: greedy scan + scatter + epilogue ----------------
__global__ __launch_bounds__(1024) void kscan(
    const float* __restrict__ logits, const float* __restrict__ pboxes,
    const int* __restrict__ img_h_p, const int* __restrict__ img_w_p,
    const unsigned* __restrict__ wsM, const unsigned short* __restrict__ wsidx,
    const unsigned* __restrict__ wmat, const unsigned char* __restrict__ wkeep,
    float* __restrict__ out, int B)
{
    __shared__ unsigned char keepq[QN];
    __shared__ unsigned skm[32];

    const int b = blockIdx.x, tid = threadIdx.x;
    const float sw = (float)(*img_w_p), sh = (float)(*img_h_p);
    const int M = (int)wsM[b];

    if (M <= NS) {
        keepq[tid] = 0; keepq[tid + 1024] = 0;
        if (tid < 64) {
            if (tid < 32) skm[tid] = 0;
            const unsigned* gm = wmat + (long)b * MATW;
            unsigned rem = 0;
            const int Ms = __builtin_amdgcn_readfirstlane(M);
            const int C = (Ms + 31) >> 5;
            unsigned rcur[32], rnxt[32];
            if (C > 0) {
                int Lc = min(tid, 31);
#pragma unroll
                for (int t = 0; t < 32; ++t) rcur[t] = gm[Lc + t * 32];
            }
            for (int c = 0; c < C; ++c) {
                if (c + 1 < C) {                      // prefetch next chunk
                    int cn = c + 1, wbn = cn >> 1, rln = 32 - 2 * wbn;
                    int Lcn = min(max(tid, 2 * wbn), 31);
                    int rb0n = rb32(wbn) + ((cn & 1) << 5) * rln + (Lcn - 2 * wbn);
#pragma unroll
                    for (int t = 0; t < 32; ++t) rnxt[t] = gm[rb0n + t * rln];
                }
                unsigned rw = (unsigned)__builtin_amdgcn_readlane((int)rem, c);
                unsigned keepmask = 0;
                int lim = min(32, Ms - (c << 5));
#pragma unroll
                for (int t = 0; t < 32; ++t) {
                    if (t < lim && !((rw >> t) & 1u)) {   // wave-uniform predicate
                        keepmask |= (1u << t);
                        rem |= rcur[t];
                        rw |= (unsigned)__builtin_amdgcn_readlane((int)rcur[t], c);
                    }
                }
                if (tid == 0) skm[c] = keepmask;
                if (c + 1 < C) {
#pragma unroll
                    for (int t = 0; t < 32; ++t) rcur[t] = rnxt[t];
                }
            }
        }
        __syncthreads();
        for (int s = tid; s < M; s += 1024)
            if ((skm[s >> 5] >> (s & 31)) & 1u) keepq[wsidx[b * NS + s]] = 1;
        __syncthreads();
    } else {
        keepq[tid] = wkeep[b * QN + tid];
        keepq[tid + 1024] = wkeep[b * QN + tid + 1024];
        __syncthreads();
    }

    // epilogue: all outputs (d_out poisoned every call)
    const long BQ = (long)B * QN;
#pragma unroll
    for (int qq = 0; qq < 2; ++qq) {
        int q = tid + qq * 1024;
        int base = b * QN + q;
        float2 l = ((const float2*)logits)[base];
        float e = expf(fminf(l.x, l.y) - fmaxf(l.x, l.y));
        float score = 1.0f / (1.0f + e);
        float4 pb = ((const float4*)pboxes)[base];
        float x1 = (pb.x - 0.5f * pb.z) * sw, y1 = (pb.y - 0.5f * pb.w) * sh;
        float x2 = (pb.x + 0.5f * pb.z) * sw, y2 = (pb.y + 0.5f * pb.w) * sh;
        int kp = keepq[q];
        out[base] = kp ? score : 0.f;
        out[BQ * 5 + base] = kp ? 1.f : 0.f;
        float4 ob;
        ob.x = kp ? truncf(x1) : 0.f;
        ob.y = kp ? truncf(y1) : 0.f;
        ob.z = kp ? truncf(x2) : 0.f;
        ob.w = kp ? truncf(y2) : 0.f;
        ((float4*)(out + BQ))[base] = ob;
    }
}

extern "C" void kernel_launch(void* const* d_in, const int* in_sizes, int n_in,
                              void* d_out, int out_size, void* d_ws, size_t ws_size,
                              hipStream_t stream) {
    const float* logits = (const float*)d_in[0];
    const float* pboxes = (const float*)d_in[1];
    const int*   img_h  = (const int*)d_in[2];
    const int*   img_w  = (const int*)d_in[3];
    float* out = (float*)d_out;
    const int B = in_sizes[0] / (QN * 2);   // 16

    char* ws = (char*)d_ws;                          // needs ~1.18 MB
    unsigned*       wsM   = (unsigned*)(ws + 0);
    unsigned short* wsidx = (unsigned short*)(ws + 256);
    unsigned*       wmat  = (unsigned*)(ws + 33024);
    unsigned char*  wkeep = (unsigned char*)(ws + 1147136);

    kbuild<<<dim3(B * 8), dim3(1024), 0, stream>>>(logits, pboxes, img_h, img_w,
                                                   wsM, wsidx, wmat, wkeep, B);
    kscan<<<dim3(B), dim3(1024), 0, stream>>>(logits, pboxes, img_h, img_w,
                                              wsM, wsidx, wmat, wkeep, out, B);
}

// Round 8
// 102.133 us; speedup vs baseline: 1.3699x; 1.0658x over previous
//
#include <hip/hip_runtime.h>
#include <math.h>

// PostProcess: B=16, Q=2048, C=2. SINGLE normal-launch kernel, grid = B*8 x 1024.
// Every block: compact + register bitonic sort (redundant, deterministic) -> its 1/8
// matrix slice -> release-store per-image flag. Slice-0 block then acquire-spins on
// its image's 8 flags, runs the single-wave greedy scan, scatters keep, epilogue.
// blk = b + 16*slice => blk%8 == b%8: all slices + consumer of image b on one XCD.
// ws: flags u32[128]@0 | mat u32[16][17408]@1024   (~1.12 MB)

#define QN    2048
#define NS    1024      // fast-path max valid boxes (E[M]=562, sd~20; M>NS ~23 sigma)
#define MATW  17408     // ragged u32 words/image = 64 * sum_{wb<16}(32-2wb)
#define MAGIC 0x5ca1ab1eu

__device__ __forceinline__ int rb32(int wb) { return 64 * wb * (33 - wb); }

__device__ __forceinline__ unsigned long long shfl_xor_u64(unsigned long long x, int m) {
    int lo = __shfl_xor((int)(unsigned)(x & 0xffffffffull), m, 64);
    int hi = __shfl_xor((int)(unsigned)(x >> 32), m, 64);
    return ((unsigned long long)(unsigned)hi << 32) | (unsigned)lo;
}

// ascending key order == score desc, idx asc (stable); invalid -> tail. Validity
// returned explicitly (valid key's top bit is SET -- R3 bug).
__device__ __forceinline__ unsigned long long score_key(float2 l, int q, bool* valid_out) {
    float mx = fmaxf(l.x, l.y), mn = fminf(l.x, l.y);
    float e = expf(mn - mx);
    float score = 1.0f / (1.0f + e);                 // max softmax prob (exact ref order)
    bool valid = (l.x >= l.y) && (score >= 0.7f);    // argmax tie -> class 0
    *valid_out = valid;
    unsigned sbits = valid ? __float_as_uint(score) : 0u;
    return ((unsigned long long)(~sbits) << 32) | (unsigned)q;
}

__global__ __launch_bounds__(1024) void kfused(
    const float* __restrict__ logits, const float* __restrict__ pboxes,
    const int* __restrict__ img_h_p, const int* __restrict__ img_w_p,
    unsigned* __restrict__ wflag, unsigned* __restrict__ wmat,
    float* __restrict__ out, int B)
{
    // fast path: skey u64[NS]@0 | sx1@8192 sy1@12288 sx2@16384 sy2@20480 sar@24576
    //            | sidxl u16[NS]@28672 | keepq u8[QN]@30720 | skm u32[32]@32768 | sM@32896
    // fallback:  skeyF u64[QN]@0 (16KB, overlaps skey/sx1/sy1) | ssupp u8[QN]@16384
    __shared__ __align__(16) char smem[32904];
    unsigned long long* skey = (unsigned long long*)smem;
    float* sx1 = (float*)(smem + 8192);
    float* sy1 = (float*)(smem + 12288);
    float* sx2 = (float*)(smem + 16384);
    float* sy2 = (float*)(smem + 20480);
    float* sar = (float*)(smem + 24576);
    unsigned short* sidxl = (unsigned short*)(smem + 28672);
    unsigned char* keepq = (unsigned char*)(smem + 30720);
    unsigned* skm = (unsigned*)(smem + 32768);
    int* sMp = (int*)(smem + 32896);

    const int blk = blockIdx.x;
    const int b = blk % B, slice = blk / B;
    const int tid = threadIdx.x, lane = tid & 63, wave = tid >> 6;
    const float sw = (float)(*img_w_p), sh = (float)(*img_h_p);

    if (tid == 0) *sMp = 0;
    keepq[tid] = 0; keepq[tid + 1024] = 0;
    if (tid < 32) skm[tid] = 0;
    __syncthreads();

    // ---- compact valid keys (ballot compaction; verified R4-R7) ----
    const unsigned long long lmask_lt = (1ull << lane) - 1ull;
#pragma unroll
    for (int qq = 0; qq < 2; ++qq) {
        int q = tid + qq * 1024;
        float2 l = ((const float2*)logits)[b * QN + q];
        bool valid;
        unsigned long long key = score_key(l, q, &valid);
        unsigned long long mb = __ballot(valid);
        int base = 0;
        if (lane == 0 && mb) base = atomicAdd(sMp, __popcll(mb));
        base = __shfl(base, 0, 64);
        if (valid) {
            int slot = base + __popcll(mb & lmask_lt);
            if (slot < NS) skey[slot] = key;
        }
    }
    __syncthreads();
    const int M = *sMp;

    if (M <= NS) {
        // ---- register bitonic sort of NS u64, 1 elem/thread (verified R4/R5) ----
        unsigned long long v = (tid < M) ? skey[tid] : ~0ull;
        __syncthreads();   // skey reused as exchange buffer
#pragma unroll
        for (int k = 2; k <= 64; k <<= 1) {
            bool dir = ((tid & k) == 0);
#pragma unroll
            for (int j = k >> 1; j > 0; j >>= 1) {
                unsigned long long o = shfl_xor_u64(v, j);
                bool takeMin = (dir == ((tid & j) == 0));
                v = ((v < o) == takeMin) ? v : o;
            }
        }
        for (int k = 128; k <= NS; k <<= 1) {
            bool dir = ((tid & k) == 0);
            for (int j = k >> 1; j >= 64; j >>= 1) {
                skey[tid] = v;
                __syncthreads();
                unsigned long long o = skey[tid ^ j];
                bool takeMin = (dir == ((tid & j) == 0));
                v = ((v < o) == takeMin) ? v : o;
                __syncthreads();
            }
#pragma unroll
            for (int j = 32; j > 0; j >>= 1) {
                unsigned long long o = shfl_xor_u64(v, j);
                bool takeMin = (dir == ((tid & j) == 0));
                v = ((v < o) == takeMin) ? v : o;
            }
        }
        // sorted SoA (padding slots zero -> iou 0)
        int qi = (int)((unsigned)v & 0xffffu);
        sidxl[tid] = (unsigned short)qi;
        float x1 = 0.f, y1 = 0.f, x2 = 0.f, y2 = 0.f, ar = 0.f;
        if (tid < M) {
            float4 pb = ((const float4*)pboxes)[b * QN + qi];
            x1 = (pb.x - 0.5f * pb.z) * sw;
            y1 = (pb.y - 0.5f * pb.w) * sh;
            x2 = (pb.x + 0.5f * pb.z) * sw;
            y2 = (pb.y + 0.5f * pb.w) * sh;
            ar = fmaxf(x2 - x1, 0.f) * fmaxf(y2 - y1, 0.f);
        }
        sx1[tid] = x1; sy1[tid] = y1; sx2[tid] = x2; sy2[tid] = y2; sar[tid] = ar;
        __syncthreads();

        // ---- matrix slice (verified R5-R7) ----
        unsigned* mat = wmat + (long)b * MATW;
        const int NG = (M + 3) >> 2;
        const int W64 = (M + 63) >> 6;
        for (int gi = slice * 16 + wave; gi < NG; gi += 128) {
            const int g = gi << 2;
            const int nr = min(4, M - g);
            const int wb = g >> 6;
            const int rl = 32 - 2 * wb;
            float ax1[4], ay1[4], ax2[4], ay2[4], aar[4];
            int rbase[4];
#pragma unroll
            for (int r = 0; r < 4; ++r) {
                int i = g + min(r, nr - 1);
                ax1[r] = sx1[i]; ay1[r] = sy1[i];
                ax2[r] = sx2[i]; ay2[r] = sy2[i]; aar[r] = sar[i];
                rbase[r] = rb32(wb) + ((g + r) & 63) * rl;
            }
            for (int w = wb; w < W64; ++w) {
                int j = (w << 6) | lane;
                float bx1 = sx1[j], by1 = sy1[j], bx2 = sx2[j], by2 = sy2[j], bar = sar[j];
#pragma unroll
                for (int r = 0; r < 4; ++r) {
                    float ltx = fmaxf(ax1[r], bx1), lty = fmaxf(ay1[r], by1);
                    float rbx = fminf(ax2[r], bx2), rby = fminf(ay2[r], by2);
                    float wx = fmaxf(rbx - ltx, 0.f), wy = fmaxf(rby - lty, 0.f);
                    float inter = wx * wy;
                    float uni = aar[r] + bar - inter;       // exact ref op order
                    float iou = inter / fmaxf(uni, 1e-9f);  // exact IEEE div
                    bool sup = (iou > 0.5f) && (j > g + r);
                    unsigned long long bal = __ballot(sup);
                    if (lane == 0 && r < nr)
                        *(unsigned long long*)(mat + rbase[r] + 2 * (w - wb)) = bal;
                }
            }
        }
        __syncthreads();   // drains this block's matrix stores (vmcnt 0 at barrier)
        if (tid == 0)
            __hip_atomic_store(&wflag[b * 8 + slice], MAGIC,
                               __ATOMIC_RELEASE, __HIP_MEMORY_SCOPE_AGENT);
        if (slice != 0) return;    // producers done; consumer block continues

        // ---- consumer: spin for all 8 slices, then single-wave greedy scan ----
        if (wave == 0) {
            const unsigned* fp = &wflag[b * 8 + (lane & 7)];
            for (;;) {
                unsigned f = (lane < 8)
                    ? __hip_atomic_load(fp, __ATOMIC_ACQUIRE, __HIP_MEMORY_SCOPE_AGENT)
                    : MAGIC;
                if (__all(f == MAGIC)) break;
                __builtin_amdgcn_s_sleep(2);
            }
            // scan (verified R5/R7): lane L = removed-word L, chunk prefetch
            const unsigned* gm = wmat + (long)b * MATW;
            unsigned rem = 0;
            const int Ms = __builtin_amdgcn_readfirstlane(M);
            const int C = (Ms + 31) >> 5;
            unsigned rcur[32], rnxt[32];
            if (C > 0) {
                int Lc = min(tid, 31);
#pragma unroll
                for (int t = 0; t < 32; ++t) rcur[t] = gm[Lc + t * 32];
            }
            for (int c = 0; c < C; ++c) {
                if (c + 1 < C) {
                    int cn = c + 1, wbn = cn >> 1, rln = 32 - 2 * wbn;
                    int Lcn = min(max(tid, 2 * wbn), 31);
                    int rb0n = rb32(wbn) + ((cn & 1) << 5) * rln + (Lcn - 2 * wbn);
#pragma unroll
                    for (int t = 0; t < 32; ++t) rnxt[t] = gm[rb0n + t * rln];
                }
                unsigned rw = (unsigned)__builtin_amdgcn_readlane((int)rem, c);
                unsigned keepmask = 0;
                int lim = min(32, Ms - (c << 5));
#pragma unroll
                for (int t = 0; t < 32; ++t) {
                    if (t < lim && !((rw >> t) & 1u)) {   // wave-uniform predicate
                        keepmask |= (1u << t);
                        rem |= rcur[t];
                        rw |= (unsigned)__builtin_amdgcn_readlane((int)rcur[t], c);
                    }
                }
                if (tid == 0) skm[c] = keepmask;
                if (c + 1 < C) {
#pragma unroll
                    for (int t = 0; t < 32; ++t) rcur[t] = rnxt[t];
                }
            }
        }
        __syncthreads();
        for (int s = tid; s < M; s += 1024)
            if ((skm[s >> 5] >> (s & 31)) & 1u) keepq[sidxl[s]] = 1;
        __syncthreads();
    } else {
        if (slice != 0) return;
        // ---- Fallback (M > NS, ~never): LDS sort + barrier greedy -> keepq ----
        unsigned long long* skeyF = (unsigned long long*)smem;
        unsigned char* ssupp = (unsigned char*)(smem + 16384);
        for (int q = tid; q < QN; q += 1024) {
            float2 l = ((const float2*)logits)[b * QN + q];
            bool valid;
            skeyF[q] = score_key(l, q, &valid);
        }
        __syncthreads();
        for (int k = 2; k <= QN; k <<= 1)
            for (int j = k >> 1; j > 0; j >>= 1) {
                int i = ((tid & ~(j - 1)) << 1) | (tid & (j - 1));
                int p = i | j;
                bool up = ((i & k) == 0);
                unsigned long long a = skeyF[i], c2 = skeyF[p];
                if ((a > c2) == up) { skeyF[i] = c2; skeyF[p] = a; }
                __syncthreads();
            }
        for (int s = tid; s < M; s += 1024) ssupp[s] = 0;
        __syncthreads();
        for (int i = 0; i < M; ++i) {
            __syncthreads();
            if (ssupp[i]) continue;
            int ia = (unsigned short)(unsigned)skeyF[i];
            float4 pa = ((const float4*)pboxes)[b * QN + ia];
            float ax1 = (pa.x - 0.5f * pa.z) * sw, ay1 = (pa.y - 0.5f * pa.w) * sh;
            float ax2 = (pa.x + 0.5f * pa.z) * sw, ay2 = (pa.y + 0.5f * pa.w) * sh;
            float areaA = fmaxf(ax2 - ax1, 0.f) * fmaxf(ay2 - ay1, 0.f);
            for (int jj = i + 1 + tid; jj < M; jj += 1024) {
                int jb = (unsigned short)(unsigned)skeyF[jj];
                float4 pq = ((const float4*)pboxes)[b * QN + jb];
                float bx1 = (pq.x - 0.5f * pq.z) * sw, by1 = (pq.y - 0.5f * pq.w) * sh;
                float bx2 = (pq.x + 0.5f * pq.z) * sw, by2 = (pq.y + 0.5f * pq.w) * sh;
                float ltx = fmaxf(ax1, bx1), lty = fmaxf(ay1, by1);
                float rbx = fminf(ax2, bx2), rby = fminf(ay2, by2);
                float wx = fmaxf(rbx - ltx, 0.f), wy = fmaxf(rby - lty, 0.f);
                float inter = wx * wy;
                float areaB = fmaxf(bx2 - bx1, 0.f) * fmaxf(by2 - by1, 0.f);
                float uni = areaA + areaB - inter;
                if (inter / fmaxf(uni, 1e-9f) > 0.5f) ssupp[jj] = 1;
            }
        }
        __syncthreads();
        for (int s = tid; s < M; s += 1024)
            if (!ssupp[s]) keepq[(unsigned short)(unsigned)skeyF[s]] = 1;
        __syncthreads();
    }

    // ---- epilogue: all outputs (d_out poisoned every call); consumer blocks only ----
    const long BQ = (long)B * QN;
#pragma unroll
    for (int qq = 0; qq < 2; ++qq) {
        int q = tid + qq * 1024;
        int base = b * QN + q;
        float2 l = ((const float2*)logits)[base];
        float e = expf(fminf(l.x, l.y) - fmaxf(l.x, l.y));
        float score = 1.0f / (1.0f + e);
        float4 pb = ((const float4*)pboxes)[base];
        float x1 = (pb.x - 0.5f * pb.z) * sw, y1 = (pb.y - 0.5f * pb.w) * sh;
        float x2 = (pb.x + 0.5f * pb.z) * sw, y2 = (pb.y + 0.5f * pb.w) * sh;
        int kp = keepq[q];
        out[base] = kp ? score : 0.f;
        out[BQ * 5 + base] = kp ? 1.f : 0.f;
        float4 ob;
        ob.x = kp ? truncf(x1) : 0.f;
        ob.y = kp ? truncf(y1) : 0.f;
        ob.z = kp ? truncf(x2) : 0.f;
        ob.w = kp ? truncf(y2) : 0.f;
        ((float4*)(out + BQ))[base] = ob;
    }
}

extern "C" void kernel_launch(void* const* d_in, const int* in_sizes, int n_in,
                              void* d_out, int out_size, void* d_ws, size_t ws_size,
                              hipStream_t stream) {
    const float* logits = (const float*)d_in[0];
    const float* pboxes = (const float*)d_in[1];
    const int*   img_h  = (const int*)d_in[2];
    const int*   img_w  = (const int*)d_in[3];
    float* out = (float*)d_out;
    const int B = in_sizes[0] / (QN * 2);   // 16

    char* ws = (char*)d_ws;                 // needs ~1.12 MB
    unsigned* wflag = (unsigned*)(ws + 0);
    unsigned* wmat  = (unsigned*)(ws + 1024);

    kfused<<<dim3(B * 8), dim3(1024), 0, stream>>>(logits, pboxes, img_h, img_w,
                                                   wflag, wmat, out, B);
}